// Round 5
// baseline (144.870 us; speedup 1.0000x reference)
//
#include <hip/hip_runtime.h>

#define NHEADS 16
#define NW 8
#define SEQ 1024
#define BATCH 8
#define EMB 128
#define KSPLIT 4
#define QSPLIT 2
#define QPT 2                  // queries per thread
#define KC (SEQ / KSPLIT)      // 256 keys per block
#define PW 132                 // proj LDS row pad (floats)

typedef _Float16 half8 __attribute__((ext_vector_type(8)));

// quantum_heads closed form for one (b,s,head) row (fp32 input):
// c[w] = cos(x[w] + theta[w]); z[0] = c1..c7; z[w>=1] = c0..cw
__device__ __forceinline__ void qrow(const float* __restrict__ xp,
                                     const float* __restrict__ th, float* z) {
    float4 a = *reinterpret_cast<const float4*>(xp);
    float4 b = *reinterpret_cast<const float4*>(xp + 4);
    float c0 = __cosf(a.x + th[0]);
    float c1 = __cosf(a.y + th[1]);
    float c2 = __cosf(a.z + th[2]);
    float c3 = __cosf(a.w + th[3]);
    float c4 = __cosf(b.x + th[4]);
    float c5 = __cosf(b.y + th[5]);
    float c6 = __cosf(b.z + th[6]);
    float c7 = __cosf(b.w + th[7]);
    float u = c1 * c2;
    u *= c3; u *= c4; u *= c5; u *= c6; u *= c7;
    z[0] = u;
    z[1] = c0 * c1;
    z[2] = z[1] * c2;
    z[3] = z[2] * c3;
    z[4] = z[3] * c4;
    z[5] = z[4] * c5;
    z[6] = z[5] * c6;
    z[7] = z[6] * c7;
}

// Kernel A: partial attention, atomic-free split-K, 2 queries/thread.
// grid = 128 bh * QSPLIT(2) * KSPLIT(4) = 1024 blocks, 256 threads.
// kv as two float4 planes: staging stores contiguous (conflict-free),
// loop reads uniform-address (broadcast). Each ds_read pair feeds 2 dots.
__global__ __launch_bounds__(256, 4) void qattn_partial(
    const float* __restrict__ x,
    const float* __restrict__ theta,
    _Float16* __restrict__ o_part,  // [KSPLIT][128 bh][1024 s][8] f16
    float* __restrict__ l_part)     // [KSPLIT][128 bh][1024 s]    f32
{
    __shared__ float kv[2 * KC * 4];        // 8 KB
    const int t   = threadIdx.x;
    const int idx = blockIdx.x;
    const int kc  = idx & (KSPLIT - 1);
    const int qc  = (idx >> 2) & (QSPLIT - 1);
    const int bh  = idx >> 3;               // 0..127
    const int b   = bh >> 4, h = bh & 15;

    float th[8];
#pragma unroll
    for (int w = 0; w < 8; ++w) th[w] = theta[w];   // wave-uniform -> s_loads

    // stage keys: 256 keys, 1 per thread; two contiguous float4 planes
    {
        const int sk = kc * KC + t;
        const float* xp = x + ((size_t)(b * SEQ + sk) * EMB + h * NW);
        float z[8];
        qrow(xp, th, z);
        *reinterpret_cast<float4*>(&kv[t * 4])          = make_float4(z[0], z[1], z[2], z[3]);
        *reinterpret_cast<float4*>(&kv[(KC + t) * 4])   = make_float4(z[4], z[5], z[6], z[7]);
    }

    // 2 queries/thread; fold 1/sqrt(8)*log2(e) into q so exp2(s) == exp(score)
    const float QS = 0.35355339059327373f * 1.4426950408889634f;
    float qv[QPT][8], oacc[QPT][8], lac[QPT];
#pragma unroll
    for (int i = 0; i < QPT; ++i) {
        const int sq = qc * 512 + i * 256 + t;
        const float* xp = x + ((size_t)(b * SEQ + sq) * EMB + h * NW);
        float z[8];
        qrow(xp, th, z);
#pragma unroll
        for (int d = 0; d < 8; ++d) { qv[i][d] = z[d] * QS; oacc[i][d] = 0.f; }
        lac[i] = 0.f;
    }

    __syncthreads();

    const float4* kvA = reinterpret_cast<const float4*>(kv);
#pragma unroll 8
    for (int k = 0; k < KC; ++k) {
        float4 ka = kvA[k];          // uniform address -> LDS broadcast
        float4 kb = kvA[KC + k];
#pragma unroll
        for (int i = 0; i < QPT; ++i) {
            float s = fmaf(qv[i][0], ka.x, fmaf(qv[i][1], ka.y, fmaf(qv[i][2], ka.z,
                      fmaf(qv[i][3], ka.w, fmaf(qv[i][4], kb.x, fmaf(qv[i][5], kb.y,
                      fmaf(qv[i][6], kb.z, qv[i][7] * kb.w)))))));
            float p = __builtin_amdgcn_exp2f(s);   // one v_exp_f32
            lac[i] += p;
            oacc[i][0] = fmaf(p, ka.x, oacc[i][0]); oacc[i][1] = fmaf(p, ka.y, oacc[i][1]);
            oacc[i][2] = fmaf(p, ka.z, oacc[i][2]); oacc[i][3] = fmaf(p, ka.w, oacc[i][3]);
            oacc[i][4] = fmaf(p, kb.x, oacc[i][4]); oacc[i][5] = fmaf(p, kb.y, oacc[i][5]);
            oacc[i][6] = fmaf(p, kb.z, oacc[i][6]); oacc[i][7] = fmaf(p, kb.w, oacc[i][7]);
        }
    }

    // store partials: o as f16x8 (16B), l as f32
#pragma unroll
    for (int i = 0; i < QPT; ++i) {
        const int sq = qc * 512 + i * 256 + t;
        half8 hv;
#pragma unroll
        for (int d = 0; d < 8; ++d) hv[d] = (_Float16)oacc[i][d];
        *reinterpret_cast<half8*>(o_part + (((size_t)kc * 128 + bh) * SEQ + sq) * 8) = hv;
        l_part[((size_t)kc * 128 + bh) * SEQ + sq] = lac[i];
    }
}

// Kernel B: out[row, e] = sum_f P[row,f] * W[e,f] + bias[e],
// P[row, h*8+d] = (sum_c o_part[c]) / (sum_c l_part[c]).
// grid = (8192/32) x (128/32) = 1024 blocks, 256 threads, 4 blocks/CU.
// 32x32 tile, 2x2 strided register tile (broadcast / 2-way LDS banking).
__global__ __launch_bounds__(256, 4) void proj_out(
    const _Float16* __restrict__ o_part,
    const float* __restrict__ l_part,
    const float* __restrict__ W,
    const float* __restrict__ bias,
    float* __restrict__ out)
{
    __shared__ float Pl[32 * PW];             // 16.9 KB
    __shared__ float Wl[32 * PW];             // 16.9 KB
    __shared__ float linv[16 * 32];           // 2 KB  [h][r]
    const int t     = threadIdx.x;
    const int row0  = blockIdx.x * 32;        // global row chunk (same b)
    const int ecol0 = blockIdx.y * 32;        // output column tile
    const int b     = row0 >> 10;
    const int s0    = row0 & 1023;

    // phase 1: 1/l for 32 rows x 16 heads (r along lanes -> coalesced)
#pragma unroll
    for (int i = 0; i < 2; ++i) {
        const int g = t + 256 * i;            // 512
        const int h = g >> 5, r = g & 31;
        const size_t a = ((size_t)(b * 16 + h) * SEQ + s0 + r);
        float l = 0.f;
#pragma unroll
        for (int c = 0; c < KSPLIT; ++c) l += l_part[(size_t)c * 128 * SEQ + a];
        linv[h * 32 + r] = 1.0f / l;
    }
    __syncthreads();

    // phase 2a: stage P (sum 4 f16 slabs, normalize)
#pragma unroll
    for (int i = 0; i < 2; ++i) {
        const int g = t + 256 * i;            // 512 cells (r,h)
        const int h = g >> 5, r = g & 31;
        const size_t base = ((size_t)(b * 16 + h) * SEQ + s0 + r) * 8;
        float v[8];
#pragma unroll
        for (int d = 0; d < 8; ++d) v[d] = 0.f;
#pragma unroll
        for (int c = 0; c < KSPLIT; ++c) {
            half8 hv = *reinterpret_cast<const half8*>(o_part + (size_t)c * 128 * SEQ * 8 + base);
#pragma unroll
            for (int d = 0; d < 8; ++d) v[d] += (float)hv[d];
        }
        const float sc = linv[h * 32 + r];
        float4 v0 = make_float4(v[0] * sc, v[1] * sc, v[2] * sc, v[3] * sc);
        float4 v1 = make_float4(v[4] * sc, v[5] * sc, v[6] * sc, v[7] * sc);
        *reinterpret_cast<float4*>(&Pl[r * PW + h * 8])     = v0;
        *reinterpret_cast<float4*>(&Pl[r * PW + h * 8 + 4]) = v1;
    }
    // phase 2b: stage W rows ecol0..ecol0+31 (coalesced)
#pragma unroll
    for (int i = 0; i < 4; ++i) {
        const int g  = t + 256 * i;           // 1024 float4 groups
        const int e  = g >> 5;
        const int k0 = (g & 31) * 4;
        *reinterpret_cast<float4*>(&Wl[e * PW + k0]) =
            *reinterpret_cast<const float4*>(W + (size_t)(ecol0 + e) * EMB + k0);
    }
    __syncthreads();

    // compute: rows {rb, rb+16}, cols {cb, cb+16}
    const int rb = t >> 4;     // 0..15
    const int cb = t & 15;     // 0..15
    float acc00 = 0.f, acc01 = 0.f, acc10 = 0.f, acc11 = 0.f;
    for (int kk = 0; kk < EMB; kk += 4) {
        float4 a0 = *reinterpret_cast<const float4*>(&Pl[rb * PW + kk]);
        float4 a1 = *reinterpret_cast<const float4*>(&Pl[(rb + 16) * PW + kk]);
        float4 w0 = *reinterpret_cast<const float4*>(&Wl[cb * PW + kk]);
        float4 w1 = *reinterpret_cast<const float4*>(&Wl[(cb + 16) * PW + kk]);
        acc00 = fmaf(a0.x, w0.x, acc00); acc00 = fmaf(a0.y, w0.y, acc00);
        acc00 = fmaf(a0.z, w0.z, acc00); acc00 = fmaf(a0.w, w0.w, acc00);
        acc01 = fmaf(a0.x, w1.x, acc01); acc01 = fmaf(a0.y, w1.y, acc01);
        acc01 = fmaf(a0.z, w1.z, acc01); acc01 = fmaf(a0.w, w1.w, acc01);
        acc10 = fmaf(a1.x, w0.x, acc10); acc10 = fmaf(a1.y, w0.y, acc10);
        acc10 = fmaf(a1.z, w0.z, acc10); acc10 = fmaf(a1.w, w0.w, acc10);
        acc11 = fmaf(a1.x, w1.x, acc11); acc11 = fmaf(a1.y, w1.y, acc11);
        acc11 = fmaf(a1.z, w1.z, acc11); acc11 = fmaf(a1.w, w1.w, acc11);
    }

    const float b0 = bias[ecol0 + cb], b1 = bias[ecol0 + cb + 16];
    out[(size_t)(row0 + rb) * EMB + ecol0 + cb]           = acc00 + b0;
    out[(size_t)(row0 + rb) * EMB + ecol0 + cb + 16]      = acc01 + b1;
    out[(size_t)(row0 + rb + 16) * EMB + ecol0 + cb]      = acc10 + b0;
    out[(size_t)(row0 + rb + 16) * EMB + ecol0 + cb + 16] = acc11 + b1;
}

extern "C" void kernel_launch(void* const* d_in, const int* in_sizes, int n_in,
                              void* d_out, int out_size, void* d_ws, size_t ws_size,
                              hipStream_t stream)
{
    const float* x     = (const float*)d_in[0];
    const float* theta = (const float*)d_in[1];
    const float* W     = (const float*)d_in[2];
    const float* bias  = (const float*)d_in[3];
    float* out = (float*)d_out;

    // workspace: o_part f16 = 4*128*1024*8*2B = 8.4 MB; l_part f32 = 4*128*1024*4B = 2.1 MB
    _Float16* o_part = (_Float16*)d_ws;
    float*    l_part = (float*)((char*)d_ws + (size_t)KSPLIT * 128 * SEQ * 8 * sizeof(_Float16));

    qattn_partial<<<128 * QSPLIT * KSPLIT, 256, 0, stream>>>(x, theta, o_part, l_part);
    proj_out<<<dim3(BATCH * SEQ / 32, EMB / 32), 256, 0, stream>>>(o_part, l_part, W, bias, out);
}

// Round 6
// 128.001 us; speedup vs baseline: 1.1318x; 1.1318x over previous
//
#include <hip/hip_runtime.h>

#define NHEADS 16
#define NW 8
#define SEQ 1024
#define BATCH 8
#define EMB 128
#define QCHUNK 64              // queries per block
#define NKH 4                  // key-quarters (threads per query)
#define KPT (SEQ / NKH)        // 256 keys per thread
#define PW 132                 // proj LDS row pad (floats)

typedef _Float16 half8 __attribute__((ext_vector_type(8)));

// quantum_heads closed form for one (b,s,head) row (fp32 input):
// c[w] = cos(x[w] + theta[w]); z[0] = c1..c7; z[w>=1] = c0..cw
__device__ __forceinline__ void qrow(const float* __restrict__ xp,
                                     const float* __restrict__ th, float* z) {
    float4 a = *reinterpret_cast<const float4*>(xp);
    float4 b = *reinterpret_cast<const float4*>(xp + 4);
    float c0 = __cosf(a.x + th[0]);
    float c1 = __cosf(a.y + th[1]);
    float c2 = __cosf(a.z + th[2]);
    float c3 = __cosf(a.w + th[3]);
    float c4 = __cosf(b.x + th[4]);
    float c5 = __cosf(b.y + th[5]);
    float c6 = __cosf(b.z + th[6]);
    float c7 = __cosf(b.w + th[7]);
    float u = c1 * c2;
    u *= c3; u *= c4; u *= c5; u *= c6; u *= c7;
    z[0] = u;
    z[1] = c0 * c1;
    z[2] = z[1] * c2;
    z[3] = z[2] * c3;
    z[4] = z[3] * c4;
    z[5] = z[4] * c5;
    z[6] = z[5] * c6;
    z[7] = z[6] * c7;
}

// Kernel A: full attention for one (b,h, 64-query chunk) per block; no split-K
// partials. Thread t: query t&63, key-quarter t>>6 (256 keys). All 1024 keys
// staged in LDS as two float4 planes (contiguous stores, broadcast reads).
// Epilogue: 4-way LDS reduce (reusing kv), normalize, write P as f16.
// grid = 128 bh * 16 qchunks = 2048 blocks; LDS 32KB -> 5 blocks/CU.
__global__ __launch_bounds__(256, 4) void qattn(
    const float* __restrict__ x,
    const float* __restrict__ theta,
    _Float16* __restrict__ P)      // [B*S][128] f16, normalized attn@h
{
    __shared__ float kv[2 * SEQ * 4];       // 32 KB
    const int t   = threadIdx.x;
    const int idx = blockIdx.x;
    const int qc  = idx & 15;               // query chunk
    const int bh  = idx >> 4;               // 0..127
    const int b   = bh >> 4, h = bh & 15;

    float th[8];
#pragma unroll
    for (int w = 0; w < 8; ++w) th[w] = theta[w];   // wave-uniform -> s_loads

    // stage all 1024 keys, 4 per thread; two contiguous float4 planes
#pragma unroll
    for (int i = 0; i < 4; ++i) {
        const int kl = t + 256 * i;
        const float* xp = x + ((size_t)(b * SEQ + kl) * EMB + h * NW);
        float z[8];
        qrow(xp, th, z);
        *reinterpret_cast<float4*>(&kv[kl * 4])         = make_float4(z[0], z[1], z[2], z[3]);
        *reinterpret_cast<float4*>(&kv[(SEQ + kl) * 4]) = make_float4(z[4], z[5], z[6], z[7]);
    }

    // this thread's query; fold 1/sqrt(8)*log2(e) so exp2(s) == exp(score)
    const float QS = 0.35355339059327373f * 1.4426950408889634f;
    const int ql = t & 63;                  // query within chunk
    const int kh = t >> 6;                  // key-quarter
    const int sq = qc * QCHUNK + ql;
    float qv[8], oacc[8];
    {
        const float* xp = x + ((size_t)(b * SEQ + sq) * EMB + h * NW);
        float z[8];
        qrow(xp, th, z);
#pragma unroll
        for (int d = 0; d < 8; ++d) { qv[d] = z[d] * QS; oacc[d] = 0.f; }
    }
    float lac = 0.f;

    __syncthreads();

    const float4* kvA = reinterpret_cast<const float4*>(kv);
    const int k0 = kh * KPT;
#pragma unroll 4
    for (int k = k0; k < k0 + KPT; ++k) {
        float4 ka = kvA[k];          // uniform address -> LDS broadcast
        float4 kb = kvA[SEQ + k];
        float s = fmaf(qv[0], ka.x, fmaf(qv[1], ka.y, fmaf(qv[2], ka.z, fmaf(qv[3], ka.w,
                  fmaf(qv[4], kb.x, fmaf(qv[5], kb.y, fmaf(qv[6], kb.z, qv[7] * kb.w)))))));
        float p = __builtin_amdgcn_exp2f(s);   // one v_exp_f32
        lac += p;
        oacc[0] = fmaf(p, ka.x, oacc[0]); oacc[1] = fmaf(p, ka.y, oacc[1]);
        oacc[2] = fmaf(p, ka.z, oacc[2]); oacc[3] = fmaf(p, ka.w, oacc[3]);
        oacc[4] = fmaf(p, kb.x, oacc[4]); oacc[5] = fmaf(p, kb.y, oacc[5]);
        oacc[6] = fmaf(p, kb.z, oacc[6]); oacc[7] = fmaf(p, kb.w, oacc[7]);
    }

    __syncthreads();                 // everyone done reading kv -> reuse as reduce buf
    float* red = kv;                 // [256][9], stride 9 (odd -> conflict-free)
#pragma unroll
    for (int d = 0; d < 8; ++d) red[t * 9 + d] = oacc[d];
    red[t * 9 + 8] = lac;
    __syncthreads();

    if (t < 64) {
        float o[8];
#pragma unroll
        for (int d = 0; d < 8; ++d) o[d] = red[t * 9 + d];
        float l = red[t * 9 + 8];
#pragma unroll
        for (int j = 1; j < NKH; ++j) {
            const int base = (t + 64 * j) * 9;
#pragma unroll
            for (int d = 0; d < 8; ++d) o[d] += red[base + d];
            l += red[base + 8];
        }
        const float inv = 1.0f / l;
        half8 hv;
#pragma unroll
        for (int d = 0; d < 8; ++d) hv[d] = (_Float16)(o[d] * inv);
        const int row = b * SEQ + qc * QCHUNK + t;
        *reinterpret_cast<half8*>(P + (size_t)row * EMB + h * NW) = hv;
    }
}

// Kernel B: out[row, e] = sum_f P[row,f] * W[e,f] + bias[e].  P is f16 [8192][128].
// grid = (8192/32) x (128/32) = 1024 blocks, 256 threads, 4 blocks/CU.
// 32x32 tile, 2x2 strided register tile (broadcast / 2-way LDS banking).
__global__ __launch_bounds__(256, 4) void proj_out(
    const _Float16* __restrict__ P,
    const float* __restrict__ W,
    const float* __restrict__ bias,
    float* __restrict__ out)
{
    __shared__ float Pl[32 * PW];             // 16.9 KB
    __shared__ float Wl[32 * PW];             // 16.9 KB
    const int t     = threadIdx.x;
    const int row0  = blockIdx.x * 32;
    const int ecol0 = blockIdx.y * 32;

    // stage P tile: 32 rows x 128 cols f16 -> f32 LDS (coalesced half8 loads)
#pragma unroll
    for (int i = 0; i < 2; ++i) {
        const int g  = t + 256 * i;           // 512 half8 chunks
        const int r  = g >> 4;
        const int c8 = (g & 15) * 8;
        half8 hv = *reinterpret_cast<const half8*>(P + (size_t)(row0 + r) * EMB + c8);
        float4 v0 = make_float4((float)hv[0], (float)hv[1], (float)hv[2], (float)hv[3]);
        float4 v1 = make_float4((float)hv[4], (float)hv[5], (float)hv[6], (float)hv[7]);
        *reinterpret_cast<float4*>(&Pl[r * PW + c8])     = v0;
        *reinterpret_cast<float4*>(&Pl[r * PW + c8 + 4]) = v1;
    }
    // stage W rows ecol0..ecol0+31 (coalesced float4)
#pragma unroll
    for (int i = 0; i < 4; ++i) {
        const int g  = t + 256 * i;           // 1024 float4 groups
        const int e  = g >> 5;
        const int k0 = (g & 31) * 4;
        *reinterpret_cast<float4*>(&Wl[e * PW + k0]) =
            *reinterpret_cast<const float4*>(W + (size_t)(ecol0 + e) * EMB + k0);
    }
    __syncthreads();

    // compute: rows {rb, rb+16}, cols {cb, cb+16}
    const int rb = t >> 4;     // 0..15
    const int cb = t & 15;     // 0..15
    float acc00 = 0.f, acc01 = 0.f, acc10 = 0.f, acc11 = 0.f;
    for (int kk = 0; kk < EMB; kk += 4) {
        float4 a0 = *reinterpret_cast<const float4*>(&Pl[rb * PW + kk]);
        float4 a1 = *reinterpret_cast<const float4*>(&Pl[(rb + 16) * PW + kk]);
        float4 w0 = *reinterpret_cast<const float4*>(&Wl[cb * PW + kk]);
        float4 w1 = *reinterpret_cast<const float4*>(&Wl[(cb + 16) * PW + kk]);
        acc00 = fmaf(a0.x, w0.x, acc00); acc00 = fmaf(a0.y, w0.y, acc00);
        acc00 = fmaf(a0.z, w0.z, acc00); acc00 = fmaf(a0.w, w0.w, acc00);
        acc01 = fmaf(a0.x, w1.x, acc01); acc01 = fmaf(a0.y, w1.y, acc01);
        acc01 = fmaf(a0.z, w1.z, acc01); acc01 = fmaf(a0.w, w1.w, acc01);
        acc10 = fmaf(a1.x, w0.x, acc10); acc10 = fmaf(a1.y, w0.y, acc10);
        acc10 = fmaf(a1.z, w0.z, acc10); acc10 = fmaf(a1.w, w0.w, acc10);
        acc11 = fmaf(a1.x, w1.x, acc11); acc11 = fmaf(a1.y, w1.y, acc11);
        acc11 = fmaf(a1.z, w1.z, acc11); acc11 = fmaf(a1.w, w1.w, acc11);
    }

    const float b0 = bias[ecol0 + cb], b1 = bias[ecol0 + cb + 16];
    out[(size_t)(row0 + rb) * EMB + ecol0 + cb]           = acc00 + b0;
    out[(size_t)(row0 + rb) * EMB + ecol0 + cb + 16]      = acc01 + b1;
    out[(size_t)(row0 + rb + 16) * EMB + ecol0 + cb]      = acc10 + b0;
    out[(size_t)(row0 + rb + 16) * EMB + ecol0 + cb + 16] = acc11 + b1;
}

extern "C" void kernel_launch(void* const* d_in, const int* in_sizes, int n_in,
                              void* d_out, int out_size, void* d_ws, size_t ws_size,
                              hipStream_t stream)
{
    const float* x     = (const float*)d_in[0];
    const float* theta = (const float*)d_in[1];
    const float* W     = (const float*)d_in[2];
    const float* bias  = (const float*)d_in[3];
    float* out = (float*)d_out;

    // workspace: P f16 [8192][128] = 2 MB
    _Float16* P = (_Float16*)d_ws;

    qattn<<<128 * 16, 256, 0, stream>>>(x, theta, P);
    proj_out<<<dim3(BATCH * SEQ / 32, EMB / 32), 256, 0, stream>>>(P, W, bias, out);
}